// Round 2
// baseline (269.460 us; speedup 1.0000x reference)
//
#include <hip/hip_runtime.h>
#include <math.h>

#define B_ 64
#define F_ 32
#define S_ 512
#define P_ 96
#define E_ 8
#define H_ 2048
#define M_ 2048   // B_*F_ rows, m = b*F_ + f

// expert kernel tiling
#define BM 128
#define BH 128
#define BK 64
#define HGROUPS 4
#define HPG (H_ / HGROUPS)   // 512
#define NHC (HPG / BH)       // 4
#define NKC (S_ / BK)        // 8

#define W1PITCH 72    // 64 + 8 skew (bf16 elems)
#define HPITCH 132    // 128 + 4 skew

typedef __bf16 bf16x8 __attribute__((ext_vector_type(8)));
typedef __bf16 bf16x4 __attribute__((ext_vector_type(4)));
typedef float f32x4 __attribute__((ext_vector_type(4)));
typedef unsigned int u32x4 __attribute__((ext_vector_type(4)));

#define MFMA16(a, b, c) __builtin_amdgcn_mfma_f32_16x16x32_bf16((a), (b), (c), 0, 0, 0)

// sigmoid-approx gelu: x * sigmoid(1.702 x) = x * rcp(1 + 2^(-2.45547 x))
__device__ __forceinline__ float fast_gelu(float x) {
  float e = __builtin_amdgcn_exp2f(-2.45546696f * x);
  return x * __builtin_amdgcn_rcpf(1.0f + e);
}

// =================== k_prep: transposes + convert + gates (role-split) ===================
// blocks [0,2048): W1 transpose  [E][S][H] f32 -> [E][H][S] bf16
// blocks [2048,2560): W2 transpose [E][H][P] f32 -> [E][P][H] bf16
// blocks [2560,3584): x convert [M][S] f32 -> bf16
// blocks [3584,4096): gates (4 rows per block)
#define PREP_GRID 4096

__device__ __forceinline__ void transpose_tile(const float* __restrict__ src,
                                               __bf16* __restrict__ dst,
                                               int R, int C, int r0, int c0, int cw,
                                               float* tile /* 64*68 */) {
  const int tid = threadIdx.x;
  {
    int row = tid >> 2;            // 64 rows
    int cseg = (tid & 3) * 16;
    const float* s = src + (size_t)(r0 + row) * C + c0;
#pragma unroll
    for (int k = 0; k < 4; ++k) {
      int c = cseg + k * 4;
      if (c < cw) *(f32x4*)&tile[row * 68 + c] = *(const f32x4*)(s + c);
    }
  }
  __syncthreads();
  {
    int r = tid & 63, cg = tid >> 6;     // 64 r-lanes (coalesced stores), 4 col groups
#pragma unroll
    for (int k = 0; k < 16; ++k) {
      int c = cg * 16 + k;
      if (c < cw) dst[(size_t)(c0 + c) * R + r0 + r] = (__bf16)tile[r * 68 + c];
    }
  }
}

__global__ __launch_bounds__(256) void k_prep(const float* __restrict__ x,
                                              const float* __restrict__ te,
                                              const float* __restrict__ Wg,
                                              const float* __restrict__ bg,
                                              const float* __restrict__ W1,
                                              const float* __restrict__ W2,
                                              __bf16* __restrict__ xbf,
                                              __bf16* __restrict__ w1t,
                                              __bf16* __restrict__ w2t,
                                              float* __restrict__ gates) {
  __shared__ float tile[64 * 68];
  const int blk = blockIdx.x;
  const int tid = threadIdx.x;

  if (blk < 2048) {                       // ---- W1 transpose
    int e = blk >> 8, tt = blk & 255;
    int r0 = (tt >> 5) * 64;              // S dim (8 tiles)
    int c0 = (tt & 31) * 64;              // H dim (32 tiles)
    transpose_tile(W1 + (size_t)e * S_ * H_, w1t + (size_t)e * H_ * S_,
                   S_, H_, r0, c0, 64, tile);
    return;
  }
  if (blk < 2560) {                       // ---- W2 transpose
    int tt = blk - 2048;
    int e = tt >> 6, u = tt & 63;
    int r0 = (u >> 1) * 64;               // H dim (32 tiles)
    int c0 = (u & 1) * 64;                // P dim (64 + 32 ragged)
    int cw = (c0 == 0) ? 64 : 32;
    transpose_tile(W2 + (size_t)e * H_ * P_, w2t + (size_t)e * P_ * H_,
                   H_, P_, r0, c0, cw, tile);
    return;
  }
  if (blk < 3584) {                       // ---- x convert
    size_t i = (size_t)(blk - 2560) * 1024 + (size_t)tid * 4;
    f32x4 v = *(const f32x4*)(x + i);
    bf16x4 o = {(__bf16)v[0], (__bf16)v[1], (__bf16)v[2], (__bf16)v[3]};
    *(bf16x4*)(xbf + i) = o;
    return;
  }
  // ---- gates: one wave per row m
  int wave = tid >> 6, lane = tid & 63;
  int m = (blk - 3584) * 4 + wave;
  const float* trow = te + (size_t)m * S_;
  float acc[E_];
#pragma unroll
  for (int e = 0; e < E_; ++e) acc[e] = 0.f;
  for (int s = lane; s < S_; s += 64) {
    float t = trow[s];
    const f32x4* wgr = (const f32x4*)(Wg + s * E_);
    f32x4 a = wgr[0], b = wgr[1];
    acc[0] += t * a[0]; acc[1] += t * a[1]; acc[2] += t * a[2]; acc[3] += t * a[3];
    acc[4] += t * b[0]; acc[5] += t * b[1]; acc[6] += t * b[2]; acc[7] += t * b[3];
  }
#pragma unroll
  for (int e = 0; e < E_; ++e) {
#pragma unroll
    for (int off = 32; off > 0; off >>= 1) acc[e] += __shfl_xor(acc[e], off, 64);
  }
  if (lane == 0) {
    float lg[E_];
    float m1 = -3.4e38f, m2 = -3.4e38f;
#pragma unroll
    for (int e = 0; e < E_; ++e) {
      float v = acc[e] + bg[e];
      lg[e] = v;
      if (v > m1) { m2 = m1; m1 = v; }
      else if (v > m2) { m2 = v; }
    }
    float den = 0.f, sm[E_];
#pragma unroll
    for (int e = 0; e < E_; ++e) { sm[e] = expf(lg[e] - m1); den += sm[e]; }
    float inv = 1.f / den;
    float dmax = -3.4e38f, dec[E_];
#pragma unroll
    for (int e = 0; e < E_; ++e) {
      float p = sm[e] * inv;
      float d = (lg[e] < m2) ? (10.f * logf(p + 1.f)) : (10.f * (expf(p) - 1.f));
      dec[e] = d;
      dmax = fmaxf(dmax, d);
    }
    float dden = 0.f;
#pragma unroll
    for (int e = 0; e < E_; ++e) { dec[e] = expf(dec[e] - dmax); dden += dec[e]; }
    float dinv = 1.f / dden;
#pragma unroll
    for (int e = 0; e < E_; ++e) gates[m * E_ + e] = dec[e] * dinv;
  }
}

// =================== k_experts (+ loss block at z==HGROUPS) ===================
// grid (E_, M_/BM, HGROUPS+1)
// GEMM1 swapped: C1[h'][m'] = sum_s W1t[h'][s] * X[m'][s]
//   A = W1 (LDS, double-buffered), B = X (direct global frags)
// gelu packed-4 writes -> Hs[m'][h'], GEMM2: Hs @ W2 (W2 frags direct global)
__global__ __launch_bounds__(256, 2) void k_experts(
    const __bf16* __restrict__ xbf,   // [M][S]
    const __bf16* __restrict__ w1t,   // [E][H][S]
    const __bf16* __restrict__ w2t,   // [E][P][H]
    const float* __restrict__ b1,     // [E][H]
    const float* __restrict__ b2,     // [E][P]
    const float* __restrict__ gates,  // [M][E]
    float* __restrict__ out)          // [M][P] (+2 loss slots)
{
  __shared__ __align__(16) __bf16 W1s[2][BM * W1PITCH];  // 2 x 18,432 B
  __shared__ __align__(16) __bf16 Hs[BM * HPITCH];       // 33,792 B

  const int tid = threadIdx.x;

  if (blockIdx.z == HGROUPS) {     // ---- loss block (+127 no-op blocks)
    if (blockIdx.x != 0 || blockIdx.y != 0) return;
    float* gsum = (float*)&W1s[0][0];      // [F_*E_]
    float* cvs  = gsum + F_ * E_;          // [F_]
    float* ents = cvs + F_;                // [F_]
    int f = tid >> 3, e = tid & 7;
    float s = 0.f;
    for (int b = 0; b < B_; ++b) s += gates[(size_t)(b * F_ + f) * E_ + e];
    gsum[f * E_ + e] = s;
    __syncthreads();
    if (tid < F_) {
      float mean = 0.f;
#pragma unroll
      for (int k = 0; k < E_; ++k) mean += gsum[tid * E_ + k];
      mean *= (1.f / E_);
      float ss = 0.f;
#pragma unroll
      for (int k = 0; k < E_; ++k) { float d = gsum[tid * E_ + k] - mean; ss += d * d; }
      float var = (float)P_ * ss / (float)(E_ * P_ - 1);
      cvs[tid] = var / (mean * mean + 1e-10f);
      float ent = 0.f;
#pragma unroll
      for (int k = 0; k < E_; ++k) { float g = gsum[tid * E_ + k] * (1.f / B_); ent += -g * logf(g + 1e-8f); }
      ents[tid] = ent * (1.f / E_);
    }
    __syncthreads();
    if (tid == 0) {
      float a = 0.f, b = 0.f;
      for (int k = 0; k < F_; ++k) { a += cvs[k]; b += ents[k]; }
      out[(size_t)M_ * P_ + 0] = a;
      out[(size_t)M_ * P_ + 1] = b;
    }
    return;
  }

  const int wave = tid >> 6, lane = tid & 63;
  const int l15 = lane & 15, quad = lane >> 4;
  const int e = blockIdx.x;
  const int m0 = blockIdx.y * BM;
  const int hbase = blockIdx.z * HPG;

  const __bf16* __restrict__ w1e = w1t + ((size_t)e * H_ + hbase) * S_;
  const __bf16* __restrict__ w2e = w2t + (size_t)e * P_ * H_ + hbase;
  const float* __restrict__ b1e = b1 + e * H_ + hbase;

  const int hh = (wave >> 1) * 64;   // wave's h-offset in 128-col chunk (GEMM1 A rows)
  const int mm = (wave & 1) * 64;    // wave's m-offset (GEMM1 B cols)

  // W1 staging decomposition: 32 rows x 64 cols per pass, 4 passes
  const int srow = tid >> 3;
  const int scol = (tid & 7) * 8;

  // X B-frag row base pointers (lane-fixed): row = m0+mm+j*16+l15, col base quad*8
  const __bf16* xrow[4];
#pragma unroll
  for (int j = 0; j < 4; ++j)
    xrow[j] = xbf + (size_t)(m0 + mm + j * 16 + l15) * S_ + quad * 8;

  const f32x4 fz = {0.f, 0.f, 0.f, 0.f};
  f32x4 acc2[2][6];
#pragma unroll
  for (int rt = 0; rt < 2; ++rt)
#pragma unroll
    for (int j = 0; j < 6; ++j) acc2[rt][j] = fz;

  const int w32 = wave * 32;   // GEMM2 wave row base

  for (int hc = 0; hc < NHC; ++hc) {
    const __bf16* __restrict__ w1hc = w1e + (size_t)(hc * BH) * S_;
    f32x4 acc1[4][4];
#pragma unroll
    for (int i = 0; i < 4; ++i)
#pragma unroll
      for (int j = 0; j < 4; ++j) acc1[i][j] = fz;

    // stage chunk 0
    u32x4 w1reg[4];
#pragma unroll
    for (int p = 0; p < 4; ++p)
      w1reg[p] = *(const u32x4*)(w1hc + (size_t)(p * 32 + srow) * S_ + scol);
#pragma unroll
    for (int p = 0; p < 4; ++p)
      *(u32x4*)&W1s[0][(p * 32 + srow) * W1PITCH + scol] = w1reg[p];
    __syncthreads();

    for (int kc = 0; kc < NKC; ++kc) {
      if (kc + 1 < NKC) {
#pragma unroll
        for (int p = 0; p < 4; ++p)
          w1reg[p] = *(const u32x4*)(w1hc + (size_t)(p * 32 + srow) * S_ + (kc + 1) * BK + scol);
      }
      const __bf16* wbuf = W1s[kc & 1];
#pragma unroll
      for (int kk = 0; kk < 2; ++kk) {
        bf16x8 a[4], b[4];
#pragma unroll
        for (int j = 0; j < 4; ++j)
          b[j] = *(const bf16x8*)(xrow[j] + kc * BK + kk * 32);
#pragma unroll
        for (int i = 0; i < 4; ++i)
          a[i] = *(const bf16x8*)&wbuf[(hh + i * 16 + l15) * W1PITCH + kk * 32 + quad * 8];
#pragma unroll
        for (int i = 0; i < 4; ++i)
#pragma unroll
          for (int j = 0; j < 4; ++j)
            acc1[i][j] = MFMA16(a[i], b[j], acc1[i][j]);
      }
      if (kc + 1 < NKC) {
#pragma unroll
        for (int p = 0; p < 4; ++p)
          *(u32x4*)&W1s[(kc + 1) & 1][(p * 32 + srow) * W1PITCH + scol] = w1reg[p];
      }
      __syncthreads();
    }

    // bias + gelu -> Hs (packed 4x bf16, consecutive h per lane)
#pragma unroll
    for (int i = 0; i < 4; ++i) {
      f32x4 bv = *(const f32x4*)&b1e[hc * BH + hh + i * 16 + quad * 4];
#pragma unroll
      for (int j = 0; j < 4; ++j) {
        bf16x4 hv;
#pragma unroll
        for (int r = 0; r < 4; ++r)
          hv[r] = (__bf16)fast_gelu(acc1[i][j][r] + bv[r]);
        *(bf16x4*)&Hs[(mm + j * 16 + l15) * HPITCH + hh + i * 16 + quad * 4] = hv;
      }
    }
    __syncthreads();

    // GEMM2: acc2 += Hs[128 x 128] @ W2chunk[128 x 96]; W2 frags direct from global
#pragma unroll
    for (int kk = 0; kk < 4; ++kk) {
      bf16x8 a0 = *(const bf16x8*)&Hs[(w32 + l15) * HPITCH + kk * 32 + quad * 8];
      bf16x8 a1 = *(const bf16x8*)&Hs[(w32 + 16 + l15) * HPITCH + kk * 32 + quad * 8];
#pragma unroll
      for (int j = 0; j < 6; ++j) {
        bf16x8 b = *(const bf16x8*)(w2e + (size_t)(j * 16 + l15) * H_ + hc * BH + kk * 32 + quad * 8);
        acc2[0][j] = MFMA16(a0, b, acc2[0][j]);
        acc2[1][j] = MFMA16(a1, b, acc2[1][j]);
      }
    }
    // next hc's staging barriers protect Hs from early rewrite
  }

  // epilogue: out[m,p] += gates[m,e] * (acc + b2 (hgroup 0 only))
#pragma unroll
  for (int rt = 0; rt < 2; ++rt) {
#pragma unroll
    for (int r = 0; r < 4; ++r) {
      int m = m0 + w32 + rt * 16 + quad * 4 + r;
      float g = gates[m * E_ + e];
#pragma unroll
      for (int j = 0; j < 6; ++j) {
        int col = j * 16 + l15;
        float v = acc2[rt][j][r];
        if (blockIdx.z == 0) v += b2[e * P_ + col];
        atomicAdd(&out[(size_t)m * P_ + col], g * v);
      }
    }
  }
}

extern "C" void kernel_launch(void* const* d_in, const int* in_sizes, int n_in,
                              void* d_out, int out_size, void* d_ws, size_t ws_size,
                              hipStream_t stream) {
  const float* x  = (const float*)d_in[0];
  const float* te = (const float*)d_in[1];
  const float* Wg = (const float*)d_in[2];
  const float* bg = (const float*)d_in[3];
  const float* W1 = (const float*)d_in[4];
  const float* b1 = (const float*)d_in[5];
  const float* W2 = (const float*)d_in[6];
  const float* b2 = (const float*)d_in[7];
  float* out = (float*)d_out;

  char* ws = (char*)d_ws;
  float* gates = (float*)ws;                                    // 65,536 B
  __bf16* xbf  = (__bf16*)(ws + 65536);                         // 2 MB
  __bf16* w1t  = (__bf16*)(ws + 65536 + 2097152);               // 16 MB
  __bf16* w2t  = (__bf16*)(ws + 65536 + 2097152 + 16777216);    // 3 MB

  hipMemsetAsync(d_out, 0, (size_t)out_size * sizeof(float), stream);
  k_prep<<<PREP_GRID, 256, 0, stream>>>(x, te, Wg, bg, W1, W2, xbf, w1t, w2t, gates);
  k_experts<<<dim3(E_, M_ / BM, HGROUPS + 1), 256, 0, stream>>>(xbf, w1t, w2t, b1, b2, gates, out);
}

// Round 3
// 268.575 us; speedup vs baseline: 1.0033x; 1.0033x over previous
//
#include <hip/hip_runtime.h>
#include <math.h>

#define B_ 64
#define F_ 32
#define S_ 512
#define P_ 96
#define E_ 8
#define H_ 2048
#define M_ 2048   // B_*F_ rows, m = b*F_ + f

// ---- k_experts tiling: 512 threads (8 waves), BM=64 rows, 512 h per block (z in [0,4)) ----
#define BM 64
#define HPB 512
#define HGROUPS 4
#define XPITCH 520    // 512 + 8 (bf16 elems); row stride 1040B (16B-aligned, balanced banks)
#define HPITCH 520
#define W2PITCH 72    // 64 + 8

typedef __bf16 bf16x8 __attribute__((ext_vector_type(8)));
typedef __bf16 bf16x4 __attribute__((ext_vector_type(4)));
typedef float f32x4 __attribute__((ext_vector_type(4)));
typedef unsigned int u32x4 __attribute__((ext_vector_type(4)));

#define MFMA16(a, b, c) __builtin_amdgcn_mfma_f32_16x16x32_bf16((a), (b), (c), 0, 0, 0)

// sigmoid-approx gelu: x * sigmoid(1.702 x)  (absmax 0.0098 in R2 — 17x margin)
__device__ __forceinline__ float fast_gelu(float x) {
  float e = __builtin_amdgcn_exp2f(-2.45546696f * x);
  return x * __builtin_amdgcn_rcpf(1.0f + e);
}

// =================== k_prep (256 threads): transposes + convert + gates ===================
// blocks [0,2048):     W1 [E][S][H] f32 -> w1t [E][H][S] bf16   (64x64 tiles)
// blocks [2048,2560):  W2 [E][H][P] f32 -> w2t [E][P][H] bf16   (64h x 48p tiles)
// blocks [2560,3072):  x convert (8 elems/thread)
// blocks [3072,3584):  gates (4 rows per block)
#define PREP_GRID 3584

__global__ __launch_bounds__(256) void k_prep(const float* __restrict__ x,
                                              const float* __restrict__ te,
                                              const float* __restrict__ Wg,
                                              const float* __restrict__ bg,
                                              const float* __restrict__ W1,
                                              const float* __restrict__ W2,
                                              __bf16* __restrict__ xbf,
                                              __bf16* __restrict__ w1t,
                                              __bf16* __restrict__ w2t,
                                              float* __restrict__ gates) {
  __shared__ float tile[64 * 65];
  const int blk = blockIdx.x;
  const int tid = threadIdx.x;

  if (blk < 2048) {                       // ---- W1 transpose: tile 64s x 64h
    int e = blk >> 8, tt = blk & 255;
    int si = tt >> 5, hi = tt & 31;       // 8 s-tiles, 32 h-tiles
    const float* src = W1 + (size_t)e * S_ * H_ + (size_t)(si * 64) * H_ + hi * 64;
    {
      int row = tid >> 2;                 // 64 s-rows
      int cb = (tid & 3) * 16;            // 16 h per seg
#pragma unroll
      for (int k = 0; k < 4; ++k) {
        f32x4 v = *(const f32x4*)(src + (size_t)row * H_ + cb + k * 4);
#pragma unroll
        for (int u = 0; u < 4; ++u) tile[row * 65 + cb + k * 4 + u] = v[u];
      }
    }
    __syncthreads();
    {
      int h = tid >> 2;                   // 64 h-rows out
      int sb = (tid & 3) * 16;            // 16 s per thread
      __bf16* dst = w1t + (size_t)e * H_ * S_ + (size_t)(hi * 64 + h) * S_ + si * 64 + sb;
      bf16x8 o0, o1;
#pragma unroll
      for (int k = 0; k < 8; ++k) o0[k] = (__bf16)tile[(sb + k) * 65 + h];
#pragma unroll
      for (int k = 0; k < 8; ++k) o1[k] = (__bf16)tile[(sb + 8 + k) * 65 + h];
      *(bf16x8*)dst = o0;
      *(bf16x8*)(dst + 8) = o1;
    }
    return;
  }
  if (blk < 2560) {                       // ---- W2 transpose: tile 64h x 48p
    int t = blk - 2048;
    int e = t >> 6, hi = (t >> 1) & 31, ph = t & 1;
    const float* src = W2 + (size_t)e * H_ * P_ + (size_t)(hi * 64) * P_ + ph * 48;
    {
      int h = tid & 63;                   // 64 h-rows
      int seg = tid >> 6;                 // 4 segs x 12 p
#pragma unroll
      for (int k = 0; k < 3; ++k) {
        f32x4 v = *(const f32x4*)(src + (size_t)h * P_ + seg * 12 + k * 4);
#pragma unroll
        for (int u = 0; u < 4; ++u) tile[h * 49 + seg * 12 + k * 4 + u] = v[u];
      }
    }
    __syncthreads();
    if (tid < 192) {
      int p = tid >> 2;                   // 48 p-rows out
      int hb = (tid & 3) * 16;            // 16 h per thread
      __bf16* dst = w2t + (size_t)e * P_ * H_ + (size_t)(ph * 48 + p) * H_ + hi * 64 + hb;
      bf16x8 o0, o1;
#pragma unroll
      for (int k = 0; k < 8; ++k) o0[k] = (__bf16)tile[(hb + k) * 49 + p];
#pragma unroll
      for (int k = 0; k < 8; ++k) o1[k] = (__bf16)tile[(hb + 8 + k) * 49 + p];
      *(bf16x8*)dst = o0;
      *(bf16x8*)(dst + 8) = o1;
    }
    return;
  }
  if (blk < 3072) {                       // ---- x convert (8/thread)
    size_t i = (size_t)(blk - 2560) * 2048 + (size_t)tid * 8;
#pragma unroll
    for (int k = 0; k < 2; ++k) {
      f32x4 v = *(const f32x4*)(x + i + k * 4);
      bf16x4 o = {(__bf16)v[0], (__bf16)v[1], (__bf16)v[2], (__bf16)v[3]};
      *(bf16x4*)(xbf + i + k * 4) = o;
    }
    return;
  }
  // ---- gates: one wave per row m
  int wave = tid >> 6, lane = tid & 63;
  int m = (blk - 3072) * 4 + wave;
  const float* trow = te + (size_t)m * S_;
  float acc[E_];
#pragma unroll
  for (int e = 0; e < E_; ++e) acc[e] = 0.f;
  for (int s = lane; s < S_; s += 64) {
    float t = trow[s];
    const f32x4* wgr = (const f32x4*)(Wg + s * E_);
    f32x4 a = wgr[0], b = wgr[1];
    acc[0] += t * a[0]; acc[1] += t * a[1]; acc[2] += t * a[2]; acc[3] += t * a[3];
    acc[4] += t * b[0]; acc[5] += t * b[1]; acc[6] += t * b[2]; acc[7] += t * b[3];
  }
#pragma unroll
  for (int e = 0; e < E_; ++e) {
#pragma unroll
    for (int off = 32; off > 0; off >>= 1) acc[e] += __shfl_xor(acc[e], off, 64);
  }
  if (lane == 0) {
    float lg[E_];
    float m1 = -3.4e38f, m2 = -3.4e38f;
#pragma unroll
    for (int e = 0; e < E_; ++e) {
      float v = acc[e] + bg[e];
      lg[e] = v;
      if (v > m1) { m2 = m1; m1 = v; }
      else if (v > m2) { m2 = v; }
    }
    float den = 0.f, sm[E_];
#pragma unroll
    for (int e = 0; e < E_; ++e) { sm[e] = expf(lg[e] - m1); den += sm[e]; }
    float inv = 1.f / den;
    float dmax = -3.4e38f, dec[E_];
#pragma unroll
    for (int e = 0; e < E_; ++e) {
      float p = sm[e] * inv;
      float d = (lg[e] < m2) ? (10.f * logf(p + 1.f)) : (10.f * (expf(p) - 1.f));
      dec[e] = d;
      dmax = fmaxf(dmax, d);
    }
    float dden = 0.f;
#pragma unroll
    for (int e = 0; e < E_; ++e) { dec[e] = expf(dec[e] - dmax); dden += dec[e]; }
    float dinv = 1.f / dden;
#pragma unroll
    for (int e = 0; e < E_; ++e) gates[m * E_ + e] = dec[e] * dinv;
  }
}

// =================== k_experts: grid (E_, M_/BM, HGROUPS+1), 512 threads ===================
// GEMM1: C1[h][m] = W1 . X^T ; A = W1 streamed global->frags (read-once),
//        B = X from LDS (staged once/block). No barriers in GEMM1.
// gelu -> Hs[m][h] (LDS). GEMM2: Hs @ W2 (W2 chunks double-buffered in LDS).
__global__ __launch_bounds__(512, 2) void k_experts(
    const __bf16* __restrict__ xbf,   // [M][S]
    const __bf16* __restrict__ w1t,   // [E][H][S]
    const __bf16* __restrict__ w2t,   // [E][P][H]
    const float* __restrict__ b1,     // [E][H]
    const float* __restrict__ b2,     // [E][P]
    const float* __restrict__ gates,  // [M][E]
    float* __restrict__ out)          // [M][P] (+2 loss slots)
{
  __shared__ __align__(16) __bf16 Xs[BM * XPITCH];        // 66,560 B
  __shared__ __align__(16) __bf16 Hs[BM * HPITCH];        // 66,560 B
  __shared__ __align__(16) __bf16 W2s[2][P_ * W2PITCH];   // 27,648 B  -> 160,768 total

  const int tid = threadIdx.x;

  if (blockIdx.z == HGROUPS) {     // ---- loss block (others no-op)
    if (blockIdx.x != 0 || blockIdx.y != 0) return;
    float* gsum = (float*)&Xs[0];          // [F_*E_]
    float* cvs  = gsum + F_ * E_;          // [F_]
    float* ents = cvs + F_;                // [F_]
    if (tid < 256) {
      int f = tid >> 3, e = tid & 7;
      float s = 0.f;
      for (int b = 0; b < B_; ++b) s += gates[(size_t)(b * F_ + f) * E_ + e];
      gsum[f * E_ + e] = s;
    }
    __syncthreads();
    if (tid < F_) {
      float mean = 0.f;
#pragma unroll
      for (int k = 0; k < E_; ++k) mean += gsum[tid * E_ + k];
      mean *= (1.f / E_);
      float ss = 0.f;
#pragma unroll
      for (int k = 0; k < E_; ++k) { float d = gsum[tid * E_ + k] - mean; ss += d * d; }
      float var = (float)P_ * ss / (float)(E_ * P_ - 1);
      cvs[tid] = var / (mean * mean + 1e-10f);
      float ent = 0.f;
#pragma unroll
      for (int k = 0; k < E_; ++k) { float g = gsum[tid * E_ + k] * (1.f / B_); ent += -g * logf(g + 1e-8f); }
      ents[tid] = ent * (1.f / E_);
    }
    __syncthreads();
    if (tid == 0) {
      float a = 0.f, b = 0.f;
      for (int k = 0; k < F_; ++k) { a += cvs[k]; b += ents[k]; }
      out[(size_t)M_ * P_ + 0] = a;
      out[(size_t)M_ * P_ + 1] = b;
    }
    return;
  }

  const int wave = tid >> 6, lane = tid & 63;
  const int l15 = lane & 15, quad = lane >> 4;
  const int e = blockIdx.x;
  const int m0 = blockIdx.y * BM;
  const int hbase = blockIdx.z * HPB;

  const __bf16* __restrict__ w2e = w2t + (size_t)e * P_ * H_ + hbase;

  // ---- stage X [64][512] once, and W2 chunks 0,1 ----
  {
    int row = tid >> 3;
    int cb = (tid & 7) * 64;
    const __bf16* src = xbf + (size_t)(m0 + row) * S_ + cb;
#pragma unroll
    for (int k = 0; k < 8; ++k)
      *(u32x4*)&Xs[row * XPITCH + cb + k * 8] = *(const u32x4*)(src + k * 8);
  }
  {
    int row = tid >> 3, cb = (tid & 7) * 8;
#pragma unroll
    for (int c = 0; c < 2; ++c) {
      *(u32x4*)&W2s[c][row * W2PITCH + cb] =
          *(const u32x4*)(w2e + (size_t)row * H_ + c * 64 + cb);
      if (tid < 256)
        *(u32x4*)&W2s[c][(64 + row) * W2PITCH + cb] =
            *(const u32x4*)(w2e + (size_t)(64 + row) * H_ + c * 64 + cb);
    }
  }
  __syncthreads();

  // ---- GEMM1: wave tile = 128h x 32m; hs = wave>>1, mh = wave&1. Barrier-free. ----
  const int hs = wave >> 1, mh = wave & 1;
  const __bf16* __restrict__ w1w = w1t + ((size_t)e * H_ + hbase + hs * 128) * S_;

  f32x4 acc1[8][2];
  const f32x4 fz = {0.f, 0.f, 0.f, 0.f};
#pragma unroll
  for (int i = 0; i < 8; ++i) { acc1[i][0] = fz; acc1[i][1] = fz; }

  const __bf16* arow[8];
#pragma unroll
  for (int i = 0; i < 8; ++i)
    arow[i] = w1w + (size_t)(i * 16 + l15) * S_ + quad * 8;
  const __bf16* brow[2];
#pragma unroll
  for (int j = 0; j < 2; ++j)
    brow[j] = &Xs[(mh * 32 + j * 16 + l15) * XPITCH + quad * 8];

  bf16x8 aA[8], bA[2], aB[8], bB[2];
#define LOAD_G1(AV, BV, t)                                            \
  {                                                                   \
    _Pragma("unroll") for (int i = 0; i < 8; ++i)                     \
        AV[i] = *(const bf16x8*)(arow[i] + (t) * 32);                 \
    _Pragma("unroll") for (int j = 0; j < 2; ++j)                     \
        BV[j] = *(const bf16x8*)(brow[j] + (t) * 32);                 \
  }
#define MFMA_G1(AV, BV)                                               \
  {                                                                   \
    _Pragma("unroll") for (int i = 0; i < 8; ++i)                     \
        _Pragma("unroll") for (int j = 0; j < 2; ++j)                 \
            acc1[i][j] = MFMA16(AV[i], BV[j], acc1[i][j]);            \
  }

  LOAD_G1(aA, bA, 0);
#pragma unroll
  for (int t = 0; t < 15; ++t) {
    if (t & 1) { LOAD_G1(aA, bA, t + 1); MFMA_G1(aB, bB); }
    else       { LOAD_G1(aB, bB, t + 1); MFMA_G1(aA, bA); }
  }
  MFMA_G1(aB, bB);   // t = 15 (odd) was loaded into B at t=14

  // ---- bias + gelu -> Hs[m][h] ----
  {
    const float* b1w = b1 + (size_t)e * H_ + hbase + hs * 128;
#pragma unroll
    for (int i = 0; i < 8; ++i) {
      f32x4 bv = *(const f32x4*)(b1w + i * 16 + quad * 4);
#pragma unroll
      for (int j = 0; j < 2; ++j) {
        bf16x4 hv;
#pragma unroll
        for (int r = 0; r < 4; ++r)
          hv[r] = (__bf16)fast_gelu(acc1[i][j][r] + bv[r]);
        *(bf16x4*)&Hs[(mh * 32 + j * 16 + l15) * HPITCH + hs * 128 + i * 16 + quad * 4] = hv;
      }
    }
  }
  __syncthreads();

  // ---- GEMM2: 64m x 96p over K=512, W2 chunks (64h) double-buffered ----
  const int mt = wave & 3, ph = wave >> 2;   // 4 m-tiles x 2 p-halves
  f32x4 acc2[3] = {fz, fz, fz};
  const int srow = tid >> 3, scb = (tid & 7) * 8;

  u32x4 s1 = {}, s2 = {};
#pragma unroll
  for (int c = 0; c < 8; ++c) {
    const bool have = (c + 2 < 8);
    if (have) {
      const __bf16* src = w2e + (c + 2) * 64;
      s1 = *(const u32x4*)(src + (size_t)srow * H_ + scb);
      if (tid < 256) s2 = *(const u32x4*)(src + (size_t)(64 + srow) * H_ + scb);
    }
    const __bf16* wb = &W2s[c & 1][0];
#pragma unroll
    for (int kk = 0; kk < 2; ++kk) {
      bf16x8 a = *(const bf16x8*)&Hs[(mt * 16 + l15) * HPITCH + c * 64 + kk * 32 + quad * 8];
#pragma unroll
      for (int j = 0; j < 3; ++j) {
        bf16x8 b = *(const bf16x8*)&wb[(ph * 48 + j * 16 + l15) * W2PITCH + kk * 32 + quad * 8];
        acc2[j] = MFMA16(a, b, acc2[j]);
      }
    }
    __syncthreads();
    if (have) {
      __bf16* dst = &W2s[c & 1][0];
      *(u32x4*)&dst[srow * W2PITCH + scb] = s1;
      if (tid < 256) *(u32x4*)&dst[(64 + srow) * W2PITCH + scb] = s2;
    }
  }

  // ---- epilogue: out[m,p] += gates[m,e] * (acc + b2 (z==0 only)) ----
#pragma unroll
  for (int r = 0; r < 4; ++r) {
    int m = m0 + mt * 16 + quad * 4 + r;
    float g = gates[m * E_ + e];
#pragma unroll
    for (int j = 0; j < 3; ++j) {
      int col = ph * 48 + j * 16 + l15;
      float v = acc2[j][r];
      if (blockIdx.z == 0) v += b2[e * P_ + col];
      atomicAdd(&out[(size_t)m * P_ + col], g * v);
    }
  }
}

extern "C" void kernel_launch(void* const* d_in, const int* in_sizes, int n_in,
                              void* d_out, int out_size, void* d_ws, size_t ws_size,
                              hipStream_t stream) {
  const float* x  = (const float*)d_in[0];
  const float* te = (const float*)d_in[1];
  const float* Wg = (const float*)d_in[2];
  const float* bg = (const float*)d_in[3];
  const float* W1 = (const float*)d_in[4];
  const float* b1 = (const float*)d_in[5];
  const float* W2 = (const float*)d_in[6];
  const float* b2 = (const float*)d_in[7];
  float* out = (float*)d_out;

  char* ws = (char*)d_ws;
  float* gates = (float*)ws;                                    // 65,536 B
  __bf16* xbf  = (__bf16*)(ws + 65536);                         // 2 MB
  __bf16* w1t  = (__bf16*)(ws + 65536 + 2097152);               // 16 MB
  __bf16* w2t  = (__bf16*)(ws + 65536 + 2097152 + 16777216);    // 3 MB

  hipMemsetAsync(d_out, 0, (size_t)out_size * sizeof(float), stream);
  k_prep<<<PREP_GRID, 256, 0, stream>>>(x, te, Wg, bg, W1, W2, xbf, w1t, w2t, gates);
  k_experts<<<dim3(E_, M_ / BM, HGROUPS + 1), 512, 0, stream>>>(xbf, w1t, w2t, b1, b2, gates, out);
}

// Round 4
// 193.738 us; speedup vs baseline: 1.3908x; 1.3863x over previous
//
#include <hip/hip_runtime.h>
#include <math.h>

#define B_ 64
#define F_ 32
#define S_ 512
#define P_ 96
#define E_ 8
#define H_ 2048
#define M_ 2048   // B_*F_ rows, m = b*F_ + f

// ---- k_experts tiling (m97-style): 256 threads, 128m x 128h tiles, BK=64 ----
#define BM 128
#define BH 128
#define BK 64
#define ZSPLIT 4
#define HPZ (H_ / ZSPLIT)   // 512 h per z-block
#define NHT (HPZ / BH)      // 4 h-chunks per block
#define NKC (S_ / BK)       // 8 k-chunks
#define HPITCH 136          // 128 + 8 skew

typedef __bf16 bf16x8 __attribute__((ext_vector_type(8)));
typedef __bf16 bf16x4 __attribute__((ext_vector_type(4)));
typedef float f32x4 __attribute__((ext_vector_type(4)));

#define MFMA16(a, b, c) __builtin_amdgcn_mfma_f32_16x16x32_bf16((a), (b), (c), 0, 0, 0)

// async global->LDS, 16B per lane; LDS dest is wave-uniform base + lane*16
#define GLL16(gp, lp) __builtin_amdgcn_global_load_lds(                     \
    (const __attribute__((address_space(1))) void*)(gp),                    \
    (__attribute__((address_space(3))) void*)(lp), 16, 0, 0)

// sigmoid-approx gelu: x * sigmoid(1.702 x)  (absmax 0.0098 measured — 17x margin)
__device__ __forceinline__ float fast_gelu(float x) {
  float e = __builtin_amdgcn_exp2f(-2.45546696f * x);
  return x * __builtin_amdgcn_rcpf(1.0f + e);
}

// =================== k_prep (256 threads): transposes + convert + gates ===================
// blocks [0,2048):     W1 [E][S][H] f32 -> w1t [E][H][S] bf16   (64x64 tiles)
// blocks [2048,2560):  W2 [E][H][P] f32 -> w2t [E][P][H] bf16   (64h x 48p tiles)
// blocks [2560,3072):  x convert (8 elems/thread)
// blocks [3072,3584):  gates (4 rows per block)
#define PREP_GRID 3584

__global__ __launch_bounds__(256) void k_prep(const float* __restrict__ x,
                                              const float* __restrict__ te,
                                              const float* __restrict__ Wg,
                                              const float* __restrict__ bg,
                                              const float* __restrict__ W1,
                                              const float* __restrict__ W2,
                                              __bf16* __restrict__ xbf,
                                              __bf16* __restrict__ w1t,
                                              __bf16* __restrict__ w2t,
                                              float* __restrict__ gates) {
  __shared__ float tile[64 * 65];
  const int blk = blockIdx.x;
  const int tid = threadIdx.x;

  if (blk < 2048) {                       // ---- W1 transpose: tile 64s x 64h
    int e = blk >> 8, tt = blk & 255;
    int si = tt >> 5, hi = tt & 31;
    const float* src = W1 + (size_t)e * S_ * H_ + (size_t)(si * 64) * H_ + hi * 64;
    {
      int row = tid >> 2;
      int cb = (tid & 3) * 16;
#pragma unroll
      for (int k = 0; k < 4; ++k) {
        f32x4 v = *(const f32x4*)(src + (size_t)row * H_ + cb + k * 4);
#pragma unroll
        for (int u = 0; u < 4; ++u) tile[row * 65 + cb + k * 4 + u] = v[u];
      }
    }
    __syncthreads();
    {
      int h = tid >> 2;
      int sb = (tid & 3) * 16;
      __bf16* dst = w1t + (size_t)e * H_ * S_ + (size_t)(hi * 64 + h) * S_ + si * 64 + sb;
      bf16x8 o0, o1;
#pragma unroll
      for (int k = 0; k < 8; ++k) o0[k] = (__bf16)tile[(sb + k) * 65 + h];
#pragma unroll
      for (int k = 0; k < 8; ++k) o1[k] = (__bf16)tile[(sb + 8 + k) * 65 + h];
      *(bf16x8*)dst = o0;
      *(bf16x8*)(dst + 8) = o1;
    }
    return;
  }
  if (blk < 2560) {                       // ---- W2 transpose: tile 64h x 48p
    int t = blk - 2048;
    int e = t >> 6, hi = (t >> 1) & 31, ph = t & 1;
    const float* src = W2 + (size_t)e * H_ * P_ + (size_t)(hi * 64) * P_ + ph * 48;
    {
      int h = tid & 63;
      int seg = tid >> 6;
#pragma unroll
      for (int k = 0; k < 3; ++k) {
        f32x4 v = *(const f32x4*)(src + (size_t)h * P_ + seg * 12 + k * 4);
#pragma unroll
        for (int u = 0; u < 4; ++u) tile[h * 49 + seg * 12 + k * 4 + u] = v[u];
      }
    }
    __syncthreads();
    if (tid < 192) {
      int p = tid >> 2;
      int hb = (tid & 3) * 16;
      __bf16* dst = w2t + (size_t)e * P_ * H_ + (size_t)(ph * 48 + p) * H_ + hi * 64 + hb;
      bf16x8 o0, o1;
#pragma unroll
      for (int k = 0; k < 8; ++k) o0[k] = (__bf16)tile[(hb + k) * 49 + p];
#pragma unroll
      for (int k = 0; k < 8; ++k) o1[k] = (__bf16)tile[(hb + 8 + k) * 49 + p];
      *(bf16x8*)dst = o0;
      *(bf16x8*)(dst + 8) = o1;
    }
    return;
  }
  if (blk < 3072) {                       // ---- x convert
    size_t i = (size_t)(blk - 2560) * 2048 + (size_t)tid * 8;
#pragma unroll
    for (int k = 0; k < 2; ++k) {
      f32x4 v = *(const f32x4*)(x + i + k * 4);
      bf16x4 o = {(__bf16)v[0], (__bf16)v[1], (__bf16)v[2], (__bf16)v[3]};
      *(bf16x4*)(xbf + i + k * 4) = o;
    }
    return;
  }
  // ---- gates: one wave per row m
  int wave = tid >> 6, lane = tid & 63;
  int m = (blk - 3072) * 4 + wave;
  const float* trow = te + (size_t)m * S_;
  float acc[E_];
#pragma unroll
  for (int e = 0; e < E_; ++e) acc[e] = 0.f;
  for (int s = lane; s < S_; s += 64) {
    float t = trow[s];
    const f32x4* wgr = (const f32x4*)(Wg + s * E_);
    f32x4 a = wgr[0], b = wgr[1];
    acc[0] += t * a[0]; acc[1] += t * a[1]; acc[2] += t * a[2]; acc[3] += t * a[3];
    acc[4] += t * b[0]; acc[5] += t * b[1]; acc[6] += t * b[2]; acc[7] += t * b[3];
  }
#pragma unroll
  for (int e = 0; e < E_; ++e) {
#pragma unroll
    for (int off = 32; off > 0; off >>= 1) acc[e] += __shfl_xor(acc[e], off, 64);
  }
  if (lane == 0) {
    float lg[E_];
    float m1 = -3.4e38f, m2 = -3.4e38f;
#pragma unroll
    for (int e = 0; e < E_; ++e) {
      float v = acc[e] + bg[e];
      lg[e] = v;
      if (v > m1) { m2 = m1; m1 = v; }
      else if (v > m2) { m2 = v; }
    }
    float den = 0.f, sm[E_];
#pragma unroll
    for (int e = 0; e < E_; ++e) { sm[e] = expf(lg[e] - m1); den += sm[e]; }
    float inv = 1.f / den;
    float dmax = -3.4e38f, dec[E_];
#pragma unroll
    for (int e = 0; e < E_; ++e) {
      float p = sm[e] * inv;
      float d = (lg[e] < m2) ? (10.f * logf(p + 1.f)) : (10.f * (expf(p) - 1.f));
      dec[e] = d;
      dmax = fmaxf(dmax, d);
    }
    float dden = 0.f;
#pragma unroll
    for (int e = 0; e < E_; ++e) { dec[e] = expf(dec[e] - dmax); dden += dec[e]; }
    float dinv = 1.f / dden;
#pragma unroll
    for (int e = 0; e < E_; ++e) gates[m * E_ + e] = dec[e] * dinv;
  }
}

// =================== k_experts: grid (E_, 16, ZSPLIT+1), 256 threads ===================
// Per block: 128m rows, 512h slice (4 chunks of 128). Per h-chunk:
//   GEMM1 (m97 structure): global_load_lds stages W1t[128h][64k] + X[128m][64k]
//   into unpadded LDS with XOR granule swizzle on the GLOBAL source address
//   (LDS dest must be lane-contiguous); ds_read_b128 frags -> MFMA.
//   gelu -> Hs[m][h]; GEMM2 accumulates acc2 (128m x 96p) across all 4 chunks.
// Single gated atomic epilogue per block.
__global__ __launch_bounds__(256, 2) void k_experts(
    const __bf16* __restrict__ xbf,   // [M][S]
    const __bf16* __restrict__ w1t,   // [E][H][S]
    const __bf16* __restrict__ w2t,   // [E][P][H]
    const float* __restrict__ b1,     // [E][H]
    const float* __restrict__ b2,     // [E][P]
    const float* __restrict__ gates,  // [M][E]
    float* __restrict__ out)          // [M][P] (+2 loss slots)
{
  __shared__ __align__(16) __bf16 W1s[BH * BK];      // 16 KB [h][k] unpadded, swizzled
  __shared__ __align__(16) __bf16 Xs[BM * BK];       // 16 KB [m][k]
  __shared__ __align__(16) __bf16 Hs[BM * HPITCH];   // 34.8 KB [m][h]  -> 67.6 KB total

  const int tid = threadIdx.x;

  if (blockIdx.z == ZSPLIT) {      // ---- loss block (others exit)
    if (blockIdx.x != 0 || blockIdx.y != 0) return;
    float* gsum = (float*)&Hs[0];
    float* cvs  = gsum + F_ * E_;
    float* ents = cvs + F_;
    int f = tid >> 3, e = tid & 7;
    float s = 0.f;
    for (int b = 0; b < B_; ++b) s += gates[(size_t)(b * F_ + f) * E_ + e];
    gsum[f * E_ + e] = s;
    __syncthreads();
    if (tid < F_) {
      float mean = 0.f;
#pragma unroll
      for (int k = 0; k < E_; ++k) mean += gsum[tid * E_ + k];
      mean *= (1.f / E_);
      float ss = 0.f;
#pragma unroll
      for (int k = 0; k < E_; ++k) { float d = gsum[tid * E_ + k] - mean; ss += d * d; }
      float var = (float)P_ * ss / (float)(E_ * P_ - 1);
      cvs[tid] = var / (mean * mean + 1e-10f);
      float ent = 0.f;
#pragma unroll
      for (int k = 0; k < E_; ++k) { float g = gsum[tid * E_ + k] * (1.f / B_); ent += -g * logf(g + 1e-8f); }
      ents[tid] = ent * (1.f / E_);
    }
    __syncthreads();
    if (tid == 0) {
      float a = 0.f, b = 0.f;
      for (int k = 0; k < F_; ++k) { a += cvs[k]; b += ents[k]; }
      out[(size_t)M_ * P_ + 0] = a;
      out[(size_t)M_ * P_ + 1] = b;
    }
    return;
  }

  const int wave = tid >> 6, lane = tid & 63;
  const int l15 = lane & 15, quad = lane >> 4;
  const int e = blockIdx.x;
  const int m0 = blockIdx.y * BM;
  const int hz = blockIdx.z * HPZ;

  // staging decomposition: lane -> (row-in-8-group, granule); swizzle sg^srl
  const int sg = lane & 7;
  const int srl = lane >> 3;
  const int gcol = ((sg ^ srl) * 8);    // swizzled source column (elements)

  const __bf16* xg = xbf + (size_t)(m0 + wave * 8 + srl) * S_ + gcol;
  const __bf16* w1base = w1t + ((size_t)e * H_ + hz + wave * 8 + srl) * S_ + gcol;
  const __bf16* w2z = w2t + (size_t)e * P_ * H_ + hz;

  const int hq = (wave >> 1) * 64;   // GEMM1 wave quadrant
  const int mq = (wave & 1) * 64;
  const int w32 = wave * 32;         // GEMM2 wave rows

  const f32x4 fz = {0.f, 0.f, 0.f, 0.f};
  f32x4 acc2[2][6];
#pragma unroll
  for (int rt = 0; rt < 2; ++rt)
#pragma unroll
    for (int j = 0; j < 6; ++j) acc2[rt][j] = fz;

  for (int ht = 0; ht < NHT; ++ht) {
    const __bf16* w1g = w1base + (size_t)(ht * BH) * S_;
    f32x4 acc1[4][4];
#pragma unroll
    for (int i = 0; i < 4; ++i)
#pragma unroll
      for (int j = 0; j < 4; ++j) acc1[i][j] = fz;

    for (int kc = 0; kc < NKC; ++kc) {
#pragma unroll
      for (int p = 0; p < 4; ++p) {
        GLL16(w1g + (size_t)(p * 32) * S_ + kc * BK, &W1s[(p * 32 + wave * 8) * BK]);
        GLL16(xg  + (size_t)(p * 32) * S_ + kc * BK, &Xs[(p * 32 + wave * 8) * BK]);
      }
      __syncthreads();   // vmcnt drain + barrier: staged tiles visible
#pragma unroll
      for (int kk = 0; kk < 2; ++kk) {
        bf16x8 a[4], b[4];
#pragma unroll
        for (int i = 0; i < 4; ++i) {
          int r = hq + i * 16 + l15;
          int g = kk * 4 + quad;
          a[i] = *(const bf16x8*)&W1s[r * BK + ((g ^ (r & 7)) * 8)];
        }
#pragma unroll
        for (int j = 0; j < 4; ++j) {
          int r = mq + j * 16 + l15;
          int g = kk * 4 + quad;
          b[j] = *(const bf16x8*)&Xs[r * BK + ((g ^ (r & 7)) * 8)];
        }
#pragma unroll
        for (int i = 0; i < 4; ++i)
#pragma unroll
          for (int j = 0; j < 4; ++j)
            acc1[i][j] = MFMA16(a[i], b[j], acc1[i][j]);
      }
      __syncthreads();   // reads done before next stage overwrites
    }

    // bias + gelu -> Hs[m][h] (C-layout: col=l15=m, row=quad*4+r=h-local)
    {
      const float* b1w = b1 + (size_t)e * H_ + hz + ht * BH + hq;
#pragma unroll
      for (int i = 0; i < 4; ++i) {
        f32x4 bv = *(const f32x4*)(b1w + i * 16 + quad * 4);
#pragma unroll
        for (int j = 0; j < 4; ++j) {
          bf16x4 hv;
#pragma unroll
          for (int r = 0; r < 4; ++r)
            hv[r] = (__bf16)fast_gelu(acc1[i][j][r] + bv[r]);
          *(bf16x4*)&Hs[(mq + j * 16 + l15) * HPITCH + hq + i * 16 + quad * 4] = hv;
        }
      }
    }
    __syncthreads();

    // GEMM2: acc2 += Hs[128m x 128h] @ W2chunk[128h x 96p]; B-frags direct from L2-hot w2t
    {
      const __bf16* w2c = w2z + ht * BH;
#pragma unroll
      for (int kk = 0; kk < 4; ++kk) {
        bf16x8 a0 = *(const bf16x8*)&Hs[(w32 + l15) * HPITCH + kk * 32 + quad * 8];
        bf16x8 a1 = *(const bf16x8*)&Hs[(w32 + 16 + l15) * HPITCH + kk * 32 + quad * 8];
#pragma unroll
        for (int j = 0; j < 6; ++j) {
          bf16x8 b = *(const bf16x8*)(w2c + (size_t)(j * 16 + l15) * H_ + kk * 32 + quad * 8);
          acc2[0][j] = MFMA16(a0, b, acc2[0][j]);
          acc2[1][j] = MFMA16(a1, b, acc2[1][j]);
        }
      }
    }
    // next ht's k-loop barriers protect Hs before its gelu rewrites it
  }

  // ---- epilogue: out[m,p] += gates[m,e] * (acc + b2 (z==0 only)) ----
#pragma unroll
  for (int rt = 0; rt < 2; ++rt) {
#pragma unroll
    for (int r = 0; r < 4; ++r) {
      int m = m0 + w32 + rt * 16 + quad * 4 + r;
      float g = gates[m * E_ + e];
#pragma unroll
      for (int j = 0; j < 6; ++j) {
        int col = j * 16 + l15;
        float v = acc2[rt][j][r];
        if (blockIdx.z == 0) v += b2[e * P_ + col];
        atomicAdd(&out[(size_t)m * P_ + col], g * v);
      }
    }
  }
}

extern "C" void kernel_launch(void* const* d_in, const int* in_sizes, int n_in,
                              void* d_out, int out_size, void* d_ws, size_t ws_size,
                              hipStream_t stream) {
  const float* x  = (const float*)d_in[0];
  const float* te = (const float*)d_in[1];
  const float* Wg = (const float*)d_in[2];
  const float* bg = (const float*)d_in[3];
  const float* W1 = (const float*)d_in[4];
  const float* b1 = (const float*)d_in[5];
  const float* W2 = (const float*)d_in[6];
  const float* b2 = (const float*)d_in[7];
  float* out = (float*)d_out;

  char* ws = (char*)d_ws;
  float* gates = (float*)ws;                                    // 65,536 B
  __bf16* xbf  = (__bf16*)(ws + 65536);                         // 2 MB
  __bf16* w1t  = (__bf16*)(ws + 65536 + 2097152);               // 16 MB
  __bf16* w2t  = (__bf16*)(ws + 65536 + 2097152 + 16777216);    // 3 MB

  hipMemsetAsync(d_out, 0, (size_t)out_size * sizeof(float), stream);
  k_prep<<<PREP_GRID, 256, 0, stream>>>(x, te, Wg, bg, W1, W2, xbf, w1t, w2t, gates);
  k_experts<<<dim3(E_, M_ / BM, ZSPLIT + 1), 256, 0, stream>>>(xbf, w1t, w2t, b1, b2, gates, out);
}